// Round 23
// baseline (20.744 us; speedup 1.0000x reference)
//
#include <hip/hip_runtime.h>
#include <math.h>

// HungarianMatcher cost matrix:
//   C[i,j] = 5*L1(pred_box_i, tgt_box_j) + 2*focal(tgt class j) - 2*GIoU
// Shapes: pred_logits [BN,NC], pred_boxes [BN,4], tgt_ids [NT], tgt_bbox [NT,4]
// BN=16*900=14400, NC=91, NT=960. Output [BN,NT] fp32.
//
// R22: R20 (best, 19.7us) with ROWS=4 (grid 3600). Per-thread fixed overhead
// (5 tbox float4 loads + 5 tid loads + focal chain) amortizes over 20
// outputs instead of 10. Table = 364 entries -> 2 softplus chains/thread
// (chip-total trans unchanged: BN*NC always). Class gathers in-loop via
// per-target LDS base ptr + compile-time row offset (R8 pattern, CSTR=5
// coprime 32 -> conflict-free). Else identical to R20: 192 threads (zero
// idle lanes), strided lane-coalesced loads, NT dword stores, one barrier.

#define ALPHA_F   0.25f
#define COST_CLS  2.0f
#define COST_BBOX 5.0f
#define COST_GIOU 2.0f
#define EPS_F     1e-8f

constexpr int THREADS = 192;          // 3 waves; 960 = 192*5

__device__ __forceinline__ float focal_entry(float x) {
    // p = sigmoid(x); sp = softplus(x); pos = A*(1-p)^2*(sp-x); neg=(1-A)*p^2*sp
    const float ex = __expf(x);
    const float p  = ex / (1.0f + ex);
    const float sp = __logf(1.0f + ex);
    const float om = 1.0f - p;
    const float pos = ALPHA_F * om * om * (sp - x);
    const float neg = (1.0f - ALPHA_F) * p * p * sp;
    return COST_CLS * (pos - neg) + COST_GIOU;   // GIoU "+2" folded in
}

// ---------------------- specialized kernel (ROWS = 4) -----------------------
template<int NC, int NT>
__global__ __launch_bounds__(THREADS) void matcher_kernel_s(
    const float* __restrict__ logits,   // [BN, NC]
    const float* __restrict__ boxes,    // [BN, 4] cxcywh
    const int*   __restrict__ tids,     // [NT]
    const float* __restrict__ tboxes,   // [NT, 4] cxcywh
    float*       __restrict__ out)      // [BN, NT]
{
    constexpr int ROWS = 4;
    constexpr int JPT  = NT / THREADS;        // 5 targets per thread (strided)
    constexpr int NTAB = ROWS * NC;           // 364 entries -> 2 chains/thread
    constexpr int CSTR = 5;                   // class stride (coprime with 32)

    __shared__ float s_cls[NC * CSTR];        // ~1.8 KB

    const int tid  = threadIdx.x;
    const int row0 = blockIdx.x * ROWS;

    // ---- issue the logit loads first (head of the transcendental chains) ----
    const float* __restrict__ lg = logits + (size_t)row0 * NC;
    const int t0 = tid;                       // < 364 always (192 threads)
    const int t1 = tid + THREADS;             // may exceed NTAB
    const float x0 = lg[t0 < NTAB ? t0 : 0];
    const float x1 = lg[t1 < NTAB ? t1 : 0];

    // ---- strided targets: ALL loads lane-coalesced ----
    float4 tb[JPT];
    const float* cp[JPT];
    #pragma unroll
    for (int k = 0; k < JPT; ++k) {
        tb[k] = reinterpret_cast<const float4*>(tboxes)[tid + k * THREADS];
        cp[k] = s_cls + tids[tid + k * THREADS] * CSTR;
    }

    // ---- focal class table: s_cls[c*5 + r], two chains per thread ----
    {
        const int r0 = t0 / NC, c0 = t0 - r0 * NC;
        s_cls[c0 * CSTR + r0] = focal_entry(x0);
        if (t1 < NTAB) {
            const int r1 = t1 / NC, c1 = t1 - r1 * NC;
            s_cls[c1 * CSTR + r1] = focal_entry(x1);
        }
    }
    __syncthreads();   // the only barrier

    float* __restrict__ obase = out + (size_t)row0 * NT + tid;
    #pragma unroll
    for (int r = 0; r < ROWS; ++r) {
        // block-uniform pred box (scalar-load path)
        const float4 pb = reinterpret_cast<const float4*>(boxes)[row0 + r];
        const float px0 = pb.x - 0.5f * pb.z, py0 = pb.y - 0.5f * pb.w;
        const float px1 = pb.x + 0.5f * pb.z, py1 = pb.y + 0.5f * pb.w;
        const float parea = pb.z * pb.w;

        #pragma unroll
        for (int k = 0; k < JPT; ++k) {
            // class gather: ds_read_b32 with compile-time row offset
            const float ctab = cp[k][r];
            const float4 t = tb[k];
            const float hw = 0.5f * t.z, hh = 0.5f * t.w;
            const float tx0 = t.x - hw, tx1 = t.x + hw;
            const float ty0 = t.y - hh, ty1 = t.y + hh;
            const float tarea = t.z * t.w;
            // L1 in cxcywh space (abs folds into VOP3 src modifiers)
            const float l1 = (fabsf(pb.x - t.x) + fabsf(pb.y - t.y))
                           + (fabsf(pb.z - t.z) + fabsf(pb.w - t.w));
            // raw intersection extents (feed enclosing box too)
            const float iwr = fminf(px1, tx1) - fmaxf(px0, tx0);
            const float ihr = fminf(py1, ty1) - fmaxf(py0, ty0);
            const float inter = fmaxf(iwr, 0.0f) * fmaxf(ihr, 0.0f);
            const float uni = (parea + tarea) - inter;
            // enclosing box via identity: cw = pw + tw - iwr
            const float cw = (pb.z + t.z) - iwr;
            const float ch = (pb.w + t.w) - ihr;
            const float carea = cw * ch;
            // C = 5*l1 + tbl[c] - 2*(inter*carea + uni^2)/(uni*carea)
            const float num  = fmaf(inter, carea, uni * uni);
            const float rcpd = __builtin_amdgcn_rcpf(uni * carea);
            const float base = fmaf(COST_BBOX, l1, ctab);
            const float v = fmaf(-2.0f * num, rcpd, base);
            // coalesced NT dword store: lane i -> out[... + i + k*192]
            __builtin_nontemporal_store(v, obase + (size_t)r * NT + k * THREADS);
        }
    }
}

// ----------------------------- generic fallback -----------------------------
constexpr int GTHREADS = 256;
constexpr int GROWS = 8;
__global__ __launch_bounds__(GTHREADS) void matcher_kernel_g(
    const float* __restrict__ logits, const float* __restrict__ boxes,
    const int* __restrict__ tids, const float* __restrict__ tboxes,
    float* __restrict__ out, int BN, int NC, int NT)
{
    extern __shared__ float s_cls_g[];
    const int tid  = threadIdx.x;
    const int row0 = blockIdx.x * GROWS;
    const int nrows = (BN - row0 < GROWS) ? (BN - row0) : GROWS;

    for (int t = tid; t < nrows * NC; t += GTHREADS) {
        const int r = t / NC, c = t - r * NC;
        const float x = logits[(size_t)(row0 + r) * NC + c];
        const float p  = 1.0f / (1.0f + expf(-x));
        const float om = 1.0f - p;
        const float neg = (1.0f - ALPHA_F) * p * p * (-logf(om + EPS_F));
        const float pos = ALPHA_F * om * om        * (-logf(p + EPS_F));
        s_cls_g[r * NC + c] = pos - neg;
    }
    __syncthreads();

    for (int r = 0; r < nrows; ++r) {
        const int row = row0 + r;
        const float4 pb = reinterpret_cast<const float4*>(boxes)[row];
        const float px0 = pb.x - 0.5f * pb.z, py0 = pb.y - 0.5f * pb.w;
        const float px1 = pb.x + 0.5f * pb.z, py1 = pb.y + 0.5f * pb.w;
        const float parea = pb.z * pb.w;
        for (int j = tid; j < NT; j += GTHREADS) {
            const float4 b = reinterpret_cast<const float4*>(tboxes)[j];
            const float bx0 = b.x - 0.5f * b.z, by0 = b.y - 0.5f * b.w;
            const float bx1 = b.x + 0.5f * b.z, by1 = b.y + 0.5f * b.w;
            const float l1 = fabsf(pb.x - b.x) + fabsf(pb.y - b.y)
                           + fabsf(pb.z - b.z) + fabsf(pb.w - b.w);
            const float iw = fmaxf(fminf(px1, bx1) - fmaxf(px0, bx0), 0.0f);
            const float ih = fmaxf(fminf(py1, by1) - fmaxf(py0, by0), 0.0f);
            const float inter = iw * ih;
            const float uni = parea + b.z * b.w - inter;
            const float iou = inter / uni;
            const float cw = fmaxf(px1, bx1) - fminf(px0, bx0);
            const float ch = fmaxf(py1, by1) - fminf(py0, by0);
            const float carea = cw * ch;
            const float giou = iou - (carea - uni) / carea;
            const float ccls = s_cls_g[r * NC + tids[j]];
            out[(size_t)row * NT + j] = COST_BBOX * l1 + COST_CLS * ccls - COST_GIOU * giou;
        }
        __syncthreads();
    }
}

extern "C" void kernel_launch(void* const* d_in, const int* in_sizes, int n_in,
                              void* d_out, int out_size, void* d_ws, size_t ws_size,
                              hipStream_t stream) {
    const float* logits = (const float*)d_in[0];
    const float* boxes  = (const float*)d_in[1];
    const int*   tids   = (const int*)d_in[2];
    const float* tboxes = (const float*)d_in[3];
    float* out = (float*)d_out;

    const int BN = in_sizes[1] / 4;       // 14400
    const int NC = in_sizes[0] / BN;      // 91
    const int NT = in_sizes[2];           // 960

    if (NC == 91 && NT == 960 && BN % 4 == 0) {
        matcher_kernel_s<91, 960><<<BN / 4, THREADS, 0, stream>>>(
            logits, boxes, tids, tboxes, out);
    } else {
        const int grid = (BN + GROWS - 1) / GROWS;
        const size_t shmem = (size_t)GROWS * NC * sizeof(float);
        matcher_kernel_g<<<grid, GTHREADS, shmem, stream>>>(
            logits, boxes, tids, tboxes, out, BN, NC, NT);
    }
}

// Round 24
// 19.655 us; speedup vs baseline: 1.0554x; 1.0554x over previous
//
#include <hip/hip_runtime.h>
#include <math.h>

// HungarianMatcher cost matrix:
//   C[i,j] = 5*L1(pred_box_i, tgt_box_j) + 2*focal(tgt class j) - 2*GIoU
// Shapes: pred_logits [BN,NC], pred_boxes [BN,4], tgt_ids [NT], tgt_bbox [NT,4]
// BN=16*900=14400, NC=91, NT=960. Output [BN,NT] fp32.
//
// R23 = R20 (session best, 19.7us), reverting R21/R22 regressions.
// Final structure and why each choice won:
//  - 192-thread blocks (3 waves, 960=192*5): ZERO idle lanes in the body
//    (256-thr variants waste wave 3: full issue for 48/64 lanes). -25% body
//    issue = -1.1us (R20, the last real win).
//  - ROWS=2, grid 7200: granularity optimum (1->23.9, 2->19.7, 4->20.7,
//    8->24.8) - deep block queue for latency hiding vs per-block overhead.
//  - strided target ownership {tid, tid+192, ...}: every global load and
//    store lane-coalesced.
//  - softplus focal: log(p)=x-sp, log(1-p)=-sp, 1 exp + 1 log per entry.
//  - single barrier; class costs prefetched to regs right after it.
//  - NT dword stores: output has no reuse; NT beat write-back by 1.6us.
// Measured floor decomposition: 8.6us NT-store HBM + ~6us VALU issue +
// ramp/overlap losses. 13 structural probes (barriers, pipelining,
// occupancy x2, coalescing, packing, addressing, split) all null.

#define ALPHA_F   0.25f
#define COST_CLS  2.0f
#define COST_BBOX 5.0f
#define COST_GIOU 2.0f
#define EPS_F     1e-8f

constexpr int THREADS = 192;          // 3 waves; 960 = 192*5

__device__ __forceinline__ float focal_entry(float x) {
    // p = sigmoid(x); sp = softplus(x); pos = A*(1-p)^2*(sp-x); neg=(1-A)*p^2*sp
    const float ex = __expf(x);
    const float p  = ex / (1.0f + ex);
    const float sp = __logf(1.0f + ex);
    const float om = 1.0f - p;
    const float pos = ALPHA_F * om * om * (sp - x);
    const float neg = (1.0f - ALPHA_F) * p * p * sp;
    return COST_CLS * (pos - neg) + COST_GIOU;   // GIoU "+2" folded in
}

// ---------------------- specialized kernel (ROWS = 2) -----------------------
template<int NC, int NT>
__global__ __launch_bounds__(THREADS) void matcher_kernel_s(
    const float* __restrict__ logits,   // [BN, NC]
    const float* __restrict__ boxes,    // [BN, 4] cxcywh
    const int*   __restrict__ tids,     // [NT]
    const float* __restrict__ tboxes,   // [NT, 4] cxcywh
    float*       __restrict__ out)      // [BN, NT]
{
    constexpr int ROWS = 2;
    constexpr int JPT  = NT / THREADS;        // 5 targets per thread (strided)
    constexpr int NTAB = ROWS * NC;           // 182 <= 192 threads
    constexpr int CSTR = 3;                   // class stride (coprime with 32)

    __shared__ float s_cls[NC * CSTR];        // ~1.1 KB

    const int tid  = threadIdx.x;
    const int row0 = blockIdx.x * ROWS;

    // ---- issue the logit load first (head of the transcendental chain) ----
    float x = 0.0f;
    if (tid < NTAB)
        x = logits[(size_t)row0 * NC + tid];

    // ---- strided targets: ALL loads lane-coalesced; all threads active ----
    float4 tb[JPT];
    int ic[JPT];
    #pragma unroll
    for (int k = 0; k < JPT; ++k) {
        tb[k] = reinterpret_cast<const float4*>(tboxes)[tid + k * THREADS];
        ic[k] = tids[tid + k * THREADS];
    }

    // ---- focal class table: s_cls[c*3 + r], one chain per thread ----
    if (tid < NTAB) {
        const int r = (tid >= NC) ? 1 : 0;
        const int c = tid - (r ? NC : 0);
        s_cls[c * CSTR + r] = focal_entry(x);
    }
    __syncthreads();   // the only barrier

    // ---- prefetch both rows' class costs to registers (ds_read) ----
    float cc0[JPT], cc1[JPT];
    #pragma unroll
    for (int k = 0; k < JPT; ++k) {
        const float* cp = s_cls + ic[k] * CSTR;
        cc0[k] = cp[0];
        cc1[k] = cp[1];
    }

    float* __restrict__ obase = out + (size_t)row0 * NT + tid;
    #pragma unroll
    for (int r = 0; r < ROWS; ++r) {
        // block-uniform pred box (scalar-load path)
        const float4 pb = reinterpret_cast<const float4*>(boxes)[row0 + r];
        const float px0 = pb.x - 0.5f * pb.z, py0 = pb.y - 0.5f * pb.w;
        const float px1 = pb.x + 0.5f * pb.z, py1 = pb.y + 0.5f * pb.w;
        const float parea = pb.z * pb.w;

        #pragma unroll
        for (int k = 0; k < JPT; ++k) {
            const float4 t = tb[k];
            const float hw = 0.5f * t.z, hh = 0.5f * t.w;
            const float tx0 = t.x - hw, tx1 = t.x + hw;
            const float ty0 = t.y - hh, ty1 = t.y + hh;
            const float tarea = t.z * t.w;
            // L1 in cxcywh space (abs folds into VOP3 src modifiers)
            const float l1 = (fabsf(pb.x - t.x) + fabsf(pb.y - t.y))
                           + (fabsf(pb.z - t.z) + fabsf(pb.w - t.w));
            // raw intersection extents (feed enclosing box too)
            const float iwr = fminf(px1, tx1) - fmaxf(px0, tx0);
            const float ihr = fminf(py1, ty1) - fmaxf(py0, ty0);
            const float inter = fmaxf(iwr, 0.0f) * fmaxf(ihr, 0.0f);
            const float uni = (parea + tarea) - inter;
            // enclosing box via identity: cw = pw + tw - iwr
            const float cw = (pb.z + t.z) - iwr;
            const float ch = (pb.w + t.w) - ihr;
            const float carea = cw * ch;
            // C = 5*l1 + tbl[c] - 2*(inter*carea + uni^2)/(uni*carea)
            const float num  = fmaf(inter, carea, uni * uni);
            const float rcpd = __builtin_amdgcn_rcpf(uni * carea);
            const float ctab = (r == 0) ? cc0[k] : cc1[k];
            const float base = fmaf(COST_BBOX, l1, ctab);
            const float v = fmaf(-2.0f * num, rcpd, base);
            // coalesced NT dword store: lane i -> out[... + i + k*192]
            __builtin_nontemporal_store(v, obase + (size_t)r * NT + k * THREADS);
        }
    }
}

// ----------------------------- generic fallback -----------------------------
constexpr int GTHREADS = 256;
constexpr int GROWS = 8;
__global__ __launch_bounds__(GTHREADS) void matcher_kernel_g(
    const float* __restrict__ logits, const float* __restrict__ boxes,
    const int* __restrict__ tids, const float* __restrict__ tboxes,
    float* __restrict__ out, int BN, int NC, int NT)
{
    extern __shared__ float s_cls_g[];
    const int tid  = threadIdx.x;
    const int row0 = blockIdx.x * GROWS;
    const int nrows = (BN - row0 < GROWS) ? (BN - row0) : GROWS;

    for (int t = tid; t < nrows * NC; t += GTHREADS) {
        const int r = t / NC, c = t - r * NC;
        const float x = logits[(size_t)(row0 + r) * NC + c];
        const float p  = 1.0f / (1.0f + expf(-x));
        const float om = 1.0f - p;
        const float neg = (1.0f - ALPHA_F) * p * p * (-logf(om + EPS_F));
        const float pos = ALPHA_F * om * om        * (-logf(p + EPS_F));
        s_cls_g[r * NC + c] = pos - neg;
    }
    __syncthreads();

    for (int r = 0; r < nrows; ++r) {
        const int row = row0 + r;
        const float4 pb = reinterpret_cast<const float4*>(boxes)[row];
        const float px0 = pb.x - 0.5f * pb.z, py0 = pb.y - 0.5f * pb.w;
        const float px1 = pb.x + 0.5f * pb.z, py1 = pb.y + 0.5f * pb.w;
        const float parea = pb.z * pb.w;
        for (int j = tid; j < NT; j += GTHREADS) {
            const float4 b = reinterpret_cast<const float4*>(tboxes)[j];
            const float bx0 = b.x - 0.5f * b.z, by0 = b.y - 0.5f * b.w;
            const float bx1 = b.x + 0.5f * b.z, by1 = b.y + 0.5f * b.w;
            const float l1 = fabsf(pb.x - b.x) + fabsf(pb.y - b.y)
                           + fabsf(pb.z - b.z) + fabsf(pb.w - b.w);
            const float iw = fmaxf(fminf(px1, bx1) - fmaxf(px0, bx0), 0.0f);
            const float ih = fmaxf(fminf(py1, by1) - fmaxf(py0, by0), 0.0f);
            const float inter = iw * ih;
            const float uni = parea + b.z * b.w - inter;
            const float iou = inter / uni;
            const float cw = fmaxf(px1, bx1) - fminf(px0, bx0);
            const float ch = fmaxf(py1, by1) - fminf(py0, by0);
            const float carea = cw * ch;
            const float giou = iou - (carea - uni) / carea;
            const float ccls = s_cls_g[r * NC + tids[j]];
            out[(size_t)row * NT + j] = COST_BBOX * l1 + COST_CLS * ccls - COST_GIOU * giou;
        }
        __syncthreads();
    }
}

extern "C" void kernel_launch(void* const* d_in, const int* in_sizes, int n_in,
                              void* d_out, int out_size, void* d_ws, size_t ws_size,
                              hipStream_t stream) {
    const float* logits = (const float*)d_in[0];
    const float* boxes  = (const float*)d_in[1];
    const int*   tids   = (const int*)d_in[2];
    const float* tboxes = (const float*)d_in[3];
    float* out = (float*)d_out;

    const int BN = in_sizes[1] / 4;       // 14400
    const int NC = in_sizes[0] / BN;      // 91
    const int NT = in_sizes[2];           // 960

    if (NC == 91 && NT == 960 && BN % 2 == 0) {
        matcher_kernel_s<91, 960><<<BN / 2, THREADS, 0, stream>>>(
            logits, boxes, tids, tboxes, out);
    } else {
        const int grid = (BN + GROWS - 1) / GROWS;
        const size_t shmem = (size_t)GROWS * NC * sizeof(float);
        matcher_kernel_g<<<grid, GTHREADS, shmem, stream>>>(
            logits, boxes, tids, tboxes, out, BN, NC, NT);
    }
}